// Round 1
// baseline (460.588 us; speedup 1.0000x reference)
//
#include <hip/hip_runtime.h>

// IterNorm (group whitening, Newton-Schulz) for x:(64,256,56,56) fp32, G=32, T=5.
// Stage 1: per-wave partial Gram via MFMA bf16 (A==B frag -> layout-robust) + partial sums.
// Stage 2: per-sample reduce + sigma + NS iterations (one wave per sample, symmetric matmuls).
// Stage 3: y = wm @ (x - mean) * weight + bias, one thread per (n, cl, hw).

#define HW 3136
#define NCH 256
#define NG 32
#define MDIM 25088  // (256/32)*3136

typedef __attribute__((ext_vector_type(8)))  short bf16x8;
typedef __attribute__((ext_vector_type(16))) float f32x16;

__device__ __forceinline__ short f2bf(float f) {
    unsigned u = __builtin_bit_cast(unsigned, f);
    unsigned r = (u + 0x7FFFu + ((u >> 16) & 1u)) >> 16;   // RNE
    return (short)r;
}

// ---------------- Stage 1: partial Gram + partial row sums ----------------
// 2048 waves: wave w -> n = w>>5, cl = (w&31)>>2, chunk = w&3 (hw0 = chunk*784).
// Lane l: group g = l&31, half = l>>5. 49 iters, each consumes 16 hw per group.
__global__ __launch_bounds__(256) void k_gram(const float* __restrict__ x,
                                              float* __restrict__ gramPart,
                                              float* __restrict__ sxPart) {
    int wid  = blockIdx.x * 4 + (threadIdx.x >> 6);   // 0..2047
    int lane = threadIdx.x & 63;
    int n    = wid >> 5;
    int r    = wid & 31;
    int cl   = r >> 2;
    int chunk = r & 3;
    int g    = lane & 31;
    int half = lane >> 5;

    const float* p = x + ((size_t)(n * NCH + g * 8 + cl)) * HW + chunk * 784 + half * 8;
    const float4* p4 = (const float4*)p;

    f32x16 acc;
    #pragma unroll
    for (int i = 0; i < 16; i++) acc[i] = 0.0f;
    float s = 0.0f;

    #pragma unroll 7
    for (int i = 0; i < 49; i++) {
        float4 a = p4[i * 4];
        float4 b = p4[i * 4 + 1];
        s += ((a.x + a.y) + (a.z + a.w)) + ((b.x + b.y) + (b.z + b.w));
        bf16x8 f;
        f[0] = f2bf(a.x); f[1] = f2bf(a.y); f[2] = f2bf(a.z); f[3] = f2bf(a.w);
        f[4] = f2bf(b.x); f[5] = f2bf(b.y); f[6] = f2bf(b.z); f[7] = f2bf(b.w);
        acc = __builtin_amdgcn_mfma_f32_32x32x16_bf16(f, f, acc, 0, 0, 0);
    }

    // C/D layout: col = lane&31, row = (reg&3) + 8*(reg>>2) + 4*(lane>>5)
    float* gp = gramPart + (size_t)wid * 1024;
    #pragma unroll
    for (int t = 0; t < 16; t++) {
        int row = (t & 3) + 8 * (t >> 2) + 4 * half;
        gp[row * 32 + g] = acc[t];
    }
    sxPart[(size_t)wid * 64 + lane] = s;
}

// ---------------- Stage 2: reduce + sigma + Newton-Schulz ----------------
// D = X @ Y with X symmetric: read X rows as columns -> contiguous float4.
__device__ __forceinline__ void mm_sym(float* __restrict__ D, const float* __restrict__ X,
                                       const float* __restrict__ Y, int tr, int tc) {
    float c[4][4];
    #pragma unroll
    for (int i = 0; i < 4; i++)
        #pragma unroll
        for (int j = 0; j < 4; j++) c[i][j] = 0.0f;
    #pragma unroll 8
    for (int k = 0; k < 32; k++) {
        float4 xa = *(const float4*)(X + k * 32 + 4 * tr);   // X[tr..][k] via symmetry
        float4 yb = *(const float4*)(Y + k * 32 + 4 * tc);
        const float* xp = &xa.x;
        const float* yp = &yb.x;
        #pragma unroll
        for (int i = 0; i < 4; i++)
            #pragma unroll
            for (int j = 0; j < 4; j++) c[i][j] = fmaf(xp[i], yp[j], c[i][j]);
    }
    #pragma unroll
    for (int i = 0; i < 4; i++) {
        float4 row = { c[i][0], c[i][1], c[i][2], c[i][3] };
        *(float4*)(D + (4 * tr + i) * 32 + 4 * tc) = row;
    }
}

__global__ __launch_bounds__(64) void k_ns(const float* __restrict__ gramPart,
                                           const float* __restrict__ sxPart,
                                           float* __restrict__ wmOut,
                                           float* __restrict__ offOut) {
    __shared__ __align__(16) float sig[1024];
    __shared__ __align__(16) float P[1024];
    __shared__ __align__(16) float A[1024];
    __shared__ __align__(16) float B[1024];
    __shared__ float meanS[32];
    __shared__ float tiS;

    int n = blockIdx.x;
    int t = threadIdx.x;

    if (t < 32) {
        float s = 0.0f;
        #pragma unroll
        for (int w = 0; w < 32; w++) {
            const float* sp = sxPart + ((size_t)n * 32 + w) * 64;
            s += sp[t] + sp[t + 32];
        }
        meanS[t] = s * (1.0f / (float)MDIM);
    }
    __syncthreads();

    for (int e = t; e < 1024; e += 64) {
        float s = 0.0f;
        #pragma unroll
        for (int w = 0; w < 32; w++) s += gramPart[((size_t)n * 32 + w) * 1024 + e];
        sig[e] = s * (1.0f / (float)MDIM) - meanS[e >> 5] * meanS[e & 31];
    }
    __syncthreads();

    if (t == 0) {
        float tr = 0.0f;
        for (int i = 0; i < 32; i++) tr += sig[i * 33];
        tiS = 1.0f / tr;
    }
    __syncthreads();
    float ti = tiS;
    for (int e = t; e < 1024; e += 64) {
        sig[e] *= ti;
        P[e] = ((e >> 5) == (e & 31)) ? 1.0f : 0.0f;
    }
    __syncthreads();

    int tr_ = t >> 3, tc = t & 7;
    for (int it = 0; it < 5; it++) {
        mm_sym(A, P, P, tr_, tc);   __syncthreads();   // A = P^2
        mm_sym(B, A, P, tr_, tc);   __syncthreads();   // B = P^3
        mm_sym(A, B, sig, tr_, tc); __syncthreads();   // A = P^3 @ sigma_n
        for (int e = t; e < 1024; e += 64) P[e] = 1.5f * P[e] - 0.5f * A[e];
        __syncthreads();
    }

    float sti = sqrtf(ti);
    for (int e = t; e < 1024; e += 64) wmOut[(size_t)n * 1024 + e] = P[e] * sti;
    if (t < 32) {
        float s = 0.0f;
        #pragma unroll
        for (int h = 0; h < 32; h++) s += P[t * 32 + h] * meanS[h];
        offOut[n * 32 + t] = s * sti;   // off[g] = sum_h wm[g][h]*mean[h]
    }
}

// ---------------- Stage 3: apply whitening ----------------
// thread -> (n, cl, hw); out[n, g*8+cl, hw] = (sum_h wm[g][h]*x[n,h*8+cl,hw] - off[g])*w + b
__global__ __launch_bounds__(256) void k_apply(const float* __restrict__ x,
                                               const float* __restrict__ wm,
                                               const float* __restrict__ off,
                                               const float* __restrict__ weight,
                                               const float* __restrict__ bias,
                                               float* __restrict__ out) {
    int n  = blockIdx.x / 98;            // uniform per block (25088/256 = 98 exact)
    int rb = blockIdx.x % 98;
    int idx = rb * 256 + threadIdx.x;    // 0..25087
    int cl = idx / HW;
    int hw = idx % HW;

    const float* xb = x + (size_t)n * NCH * HW + cl * HW + hw;
    float xv[32];
    #pragma unroll
    for (int h = 0; h < 32; h++) xv[h] = xb[(size_t)h * 8 * HW];

    const float* wmn  = wm + (size_t)n * 1024;   // uniform pointer -> scalar loads
    const float* offn = off + n * 32;
    float* ob = out + (size_t)n * NCH * HW + cl * HW + hw;

    for (int g = 0; g < 32; g++) {
        float s = -offn[g];
        #pragma unroll
        for (int h = 0; h < 32; h++) s = fmaf(wmn[g * 32 + h], xv[h], s);
        int c = g * 8 + cl;
        ob[(size_t)g * 8 * HW] = s * weight[c] + bias[c];
    }
}

extern "C" void kernel_launch(void* const* d_in, const int* in_sizes, int n_in,
                              void* d_out, int out_size, void* d_ws, size_t ws_size,
                              hipStream_t stream) {
    const float* x      = (const float*)d_in[0];
    const float* weight = (const float*)d_in[1];
    const float* bias   = (const float*)d_in[2];
    float* out = (float*)d_out;

    // ws layout (floats): gramPart 2048*1024 | sxPart 2048*64 | wm 64*1024 | off 64*32  (~9.2 MB)
    float* ws       = (float*)d_ws;
    float* gramPart = ws;
    float* sxPart   = gramPart + (size_t)2048 * 1024;
    float* wmOut    = sxPart + (size_t)2048 * 64;
    float* offOut   = wmOut + (size_t)64 * 1024;

    hipLaunchKernelGGL(k_gram,  dim3(512),  dim3(256), 0, stream, x, gramPart, sxPart);
    hipLaunchKernelGGL(k_ns,    dim3(64),   dim3(64),  0, stream, gramPart, sxPart, wmOut, offOut);
    hipLaunchKernelGGL(k_apply, dim3(6272), dim3(256), 0, stream, x, wmOut, offOut, weight, bias, out);
}